// Round 1
// baseline (4490.338 us; speedup 1.0000x reference)
//
#include <hip/hip_runtime.h>

#define NN 32768
#define NE 131072
#define NB 512
#define SL 1000

// ---------------- degree / normalization ----------------
__global__ void k_deg(const int* __restrict__ dst, float* __restrict__ deg, int E) {
  int e = blockIdx.x * 256 + threadIdx.x;
  if (e < E) atomicAdd(&deg[dst[e]], 1.0f);
}
__global__ void k_dis(float* d, int N) {
  int i = blockIdx.x * 256 + threadIdx.x;
  if (i < N) d[i] = rsqrtf(1.0f + d[i]);
}

// ---------------- generic dense layer: out[n][co] = (relu)(bias + in[n][:] @ W) ----------------
// W layout [K][C_OUT] (co contiguous). Thread computes 4 consecutive co for one n.
template<int C_OUT, int K, bool RELU, bool BIAS>
__launch_bounds__(256)
__global__ void k_fc(const float* __restrict__ in, const float* __restrict__ W,
                     const float* __restrict__ bias, float* __restrict__ out, int N) {
  constexpr int CO4 = C_OUT / 4;
  int gid = blockIdx.x * 256 + threadIdx.x;
  int n = gid / CO4;
  if (n >= N) return;
  int co = (gid - n * CO4) * 4;
  const float* row = in + (long)n * K;
  float ax = 0.f, ay = 0.f, az = 0.f, aw = 0.f;
  if (BIAS) {
    float4 b4 = *(const float4*)&bias[co];
    ax = b4.x; ay = b4.y; az = b4.z; aw = b4.w;
  }
#pragma unroll 4
  for (int ci = 0; ci < K; ++ci) {
    float a = row[ci];
    float4 w = *(const float4*)&W[(long)ci * C_OUT + co];
    ax += a * w.x; ay += a * w.y; az += a * w.z; aw += a * w.w;
  }
  if (RELU) {
    ax = fmaxf(ax, 0.f); ay = fmaxf(ay, 0.f); az = fmaxf(az, 0.f); aw = fmaxf(aw, 0.f);
  }
  float4 o; o.x = ax; o.y = ay; o.z = az; o.w = aw;
  *(float4*)&out[(long)n * C_OUT + co] = o;
}

// ---------------- GCN self-loop term: agg = xw * dis[n]^2 ----------------
template<int C>
__global__ void k_selfscale(const float* __restrict__ xw, const float* __restrict__ dis,
                            float* __restrict__ agg, int N) {
  constexpr int C4 = C / 4;
  int gid = blockIdx.x * 256 + threadIdx.x;
  int n = gid / C4;
  if (n >= N) return;
  int c = (gid - n * C4) * 4;
  float s = dis[n]; s = s * s;
  float4 v = *(const float4*)&xw[(long)n * C + c];
  v.x *= s; v.y *= s; v.z *= s; v.w *= s;
  *(float4*)&agg[(long)n * C + c] = v;
}

// ---------------- edge scatter: agg[dst] += xw[src] * dis[src]*dis[dst] ----------------
template<int C>
__global__ void k_scatter(const float* __restrict__ xw, const float* __restrict__ dis,
                          const int* __restrict__ src, const int* __restrict__ dst,
                          float* __restrict__ agg, int E) {
  constexpr int C4 = C / 4;
  int gid = blockIdx.x * 256 + threadIdx.x;
  int e = gid / C4;
  if (e >= E) return;
  int c = (gid - e * C4) * 4;
  int s = src[e], d = dst[e];
  float coef = dis[s] * dis[d];
  float4 v = *(const float4*)&xw[(long)s * C + c];
  float* p = &agg[(long)d * C + c];
  atomicAdd(p + 0, v.x * coef);
  atomicAdd(p + 1, v.y * coef);
  atomicAdd(p + 2, v.z * coef);
  atomicAdd(p + 3, v.w * coef);
}

// ---------------- batchnorm: stats (sum, sumsq per channel) ----------------
template<int C>
__global__ void k_bnstats(const float* __restrict__ h, float* __restrict__ stats, int N) {
  constexpr int RPB = 256 / C;
  int c = threadIdx.x % C;
  int r = threadIdx.x / C;
  float s = 0.f, ss = 0.f;
  for (int n = blockIdx.x * RPB + r; n < N; n += gridDim.x * RPB) {
    float v = h[(long)n * C + c];
    s += v; ss += v * v;
  }
  __shared__ float ls[256], lss[256];
  ls[threadIdx.x] = s; lss[threadIdx.x] = ss;
  __syncthreads();
  if (threadIdx.x < C) {
    float st = 0.f, sst = 0.f;
#pragma unroll
    for (int r2 = 0; r2 < RPB; ++r2) { st += ls[c + r2 * C]; sst += lss[c + r2 * C]; }
    atomicAdd(&stats[c], st);
    atomicAdd(&stats[C + c], sst);
  }
}

// stats -> (scale, shift); note GCN bias b is dropped upstream: _bn(x+b)==_bn(x)
template<int C>
__global__ void k_bnfinal(float* stats, const float* __restrict__ g,
                          const float* __restrict__ bt, int N) {
  int c = threadIdx.x;
  float m = stats[c] / (float)N;
  float v = stats[C + c] / (float)N - m * m;
  float sc = g[c] * rsqrtf(v + 1e-5f);
  stats[c] = sc;
  stats[C + c] = bt[c] - m * sc;
}

template<int C>
__global__ void k_bnrelu(float* __restrict__ h, const float* __restrict__ stats, int N) {
  constexpr int C4 = C / 4;
  int gid = blockIdx.x * 256 + threadIdx.x;
  int n = gid / C4;
  if (n >= N) return;
  int c = (gid - n * C4) * 4;
  float4 v = *(float4*)&h[(long)n * C + c];
  float4 sc = *(const float4*)&stats[c];
  float4 sh = *(const float4*)&stats[C + c];
  v.x = fmaxf(v.x * sc.x + sh.x, 0.f);
  v.y = fmaxf(v.y * sc.y + sh.y, 0.f);
  v.z = fmaxf(v.z * sc.z + sh.z, 0.f);
  v.w = fmaxf(v.w * sc.w + sh.w, 0.f);
  *(float4*)&h[(long)n * C + c] = v;
}

// ---------------- graph mean-pool into cbuf[:, 0:128] ----------------
__global__ void k_pool(const float* __restrict__ h, const int* __restrict__ batch,
                       float* __restrict__ cbuf, float* __restrict__ cnt, int N) {
  int gid = blockIdx.x * 256 + threadIdx.x;
  int n = gid >> 5;
  if (n >= N) return;
  int c = (gid & 31) * 4;
  int b = batch[n];
  float4 v = *(const float4*)&h[(long)n * 128 + c];
  float* p = &cbuf[b * 224 + c];
  atomicAdd(p + 0, v.x); atomicAdd(p + 1, v.y);
  atomicAdd(p + 2, v.z); atomicAdd(p + 3, v.w);
  if ((gid & 31) == 0) atomicAdd(&cnt[b], 1.0f);
}
__global__ void k_pooldiv(float* cbuf, const float* __restrict__ cnt) {
  int gid = blockIdx.x * 256 + threadIdx.x;  // 512*128
  int b = gid >> 7, c = gid & 127;
  cbuf[b * 224 + c] *= 1.0f / fmaxf(cnt[b], 1.0f);
}

// ---------------- fused protein encoder: emb-gather -> conv1 -> conv2 -> conv3 -> max ----------------
// Tile of T3=48 conv3 outputs per block. All intermediates in LDS (56.6 KB).
// Halo mapping for tile base t0 = tile*48:
//   s_in[j]  <-> input position p  = t0 - 6 + j, j in [0,63)
//   s_c1[j]  <-> conv1 output l1   = t0 - 5 + j, j in [0,60)
//   s_c2[j]  <-> conv2 output l2   = t0 - 3 + j, j in [0,55)
//   conv3 output l3 = t0 + j3, j3 in [0,48), valid l3 < 997
// Out-of-range intermediate rows are stored as 0 (zero padding semantics).
// a[] reads past the written range only feed accumulators that are discarded.
__launch_bounds__(256)
__global__ void conv_fused(const int* __restrict__ seq, const float* __restrict__ emb,
                           const float* __restrict__ ck1, const float* __restrict__ cb1,
                           const float* __restrict__ ck2, const float* __restrict__ cb2,
                           const float* __restrict__ ck3, const float* __restrict__ cb3,
                           float* __restrict__ outmax) {
  __shared__ float s_in[67][128];  // rows 63..66 never written, never used by kept accs
  __shared__ float s_c1[61][32];   // row 60 same
  __shared__ float s_c2[55][64];
  __shared__ int s_max[96];

  int tid = threadIdx.x;
  int tile = blockIdx.x;
  int b = blockIdx.y;
  int t0 = tile * 48;

  if (tid < 96) s_max[tid] = 0;

  // gather embeddings (emb row 0 is the zeroed padding row)
  for (int idx = tid; idx < 63 * 128; idx += 256) {
    int j = idx >> 7, ci = idx & 127;
    int p = t0 - 6 + j;
    float v = 0.f;
    if (p >= 0 && p < SL) {
      int tok = seq[b * SL + p];
      v = emb[tok * 128 + ci];
    }
    s_in[j][ci] = v;
  }
  __syncthreads();

  // ---- stage 1: conv1  Cin=128 K=4 Cout=32, outputs j in [0,60)
  {
    int co = tid & 31, jg = tid >> 5;
    float acc[8];
    float bv = cb1[co];
#pragma unroll
    for (int i = 0; i < 8; ++i) acc[i] = bv;
    for (int c4 = 0; c4 < 32; ++c4) {
      float a[11][4];
#pragma unroll
      for (int r = 0; r < 11; ++r) {
        float4 t4 = *(const float4*)&s_in[jg * 8 + r][c4 * 4];
        a[r][0] = t4.x; a[r][1] = t4.y; a[r][2] = t4.z; a[r][3] = t4.w;
      }
      float wf[16];
      const float* wp = ck1 + co * 512 + c4 * 16;  // [co][ci][k], 16 contiguous floats
#pragma unroll
      for (int q = 0; q < 4; ++q) {
        float4 w4 = *(const float4*)(wp + q * 4);
        wf[q * 4 + 0] = w4.x; wf[q * 4 + 1] = w4.y; wf[q * 4 + 2] = w4.z; wf[q * 4 + 3] = w4.w;
      }
#pragma unroll
      for (int cc = 0; cc < 4; ++cc)
#pragma unroll
        for (int k = 0; k < 4; ++k) {
          float wv = wf[cc * 4 + k];
#pragma unroll
          for (int i = 0; i < 8; ++i) acc[i] += a[i + k][cc] * wv;
        }
    }
#pragma unroll
    for (int i = 0; i < 8; ++i) {
      int j = jg * 8 + i;
      if (j < 60) {
        int l1 = t0 - 5 + j;
        s_c1[j][co] = (l1 >= 0 && l1 < 999) ? fmaxf(acc[i], 0.f) : 0.f;
      }
    }
  }
  __syncthreads();

  // ---- stage 2: conv2  Cin=32 K=6 Cout=64, outputs j in [0,55)
  {
    int cp = tid & 31, jg = tid >> 5;
    int co0 = cp * 2;
    float acc[7][2];
    {
      float b0 = cb2[co0], b1 = cb2[co0 + 1];
#pragma unroll
      for (int i = 0; i < 7; ++i) { acc[i][0] = b0; acc[i][1] = b1; }
    }
    for (int c4 = 0; c4 < 8; ++c4) {
      float a[12][4];
#pragma unroll
      for (int r = 0; r < 12; ++r) {
        float4 t4 = *(const float4*)&s_c1[jg * 7 + r][c4 * 4];
        a[r][0] = t4.x; a[r][1] = t4.y; a[r][2] = t4.z; a[r][3] = t4.w;
      }
      float wf[2][24];
#pragma unroll
      for (int t = 0; t < 2; ++t) {
        const float* wp = ck2 + (co0 + t) * 192 + c4 * 24;  // 24 contiguous floats
#pragma unroll
        for (int q = 0; q < 6; ++q) {
          float4 w4 = *(const float4*)(wp + q * 4);
          wf[t][q * 4 + 0] = w4.x; wf[t][q * 4 + 1] = w4.y;
          wf[t][q * 4 + 2] = w4.z; wf[t][q * 4 + 3] = w4.w;
        }
      }
#pragma unroll
      for (int cc = 0; cc < 4; ++cc)
#pragma unroll
        for (int k = 0; k < 6; ++k) {
          float w0 = wf[0][cc * 6 + k], w1 = wf[1][cc * 6 + k];
#pragma unroll
          for (int i = 0; i < 7; ++i) {
            acc[i][0] += a[i + k][cc] * w0;
            acc[i][1] += a[i + k][cc] * w1;
          }
        }
    }
#pragma unroll
    for (int i = 0; i < 7; ++i) {
      int j = jg * 7 + i;
      if (j < 55) {
        int l2 = t0 - 3 + j;
        bool ok = (l2 >= 0 && l2 < 998);
        s_c2[j][co0] = ok ? fmaxf(acc[i][0], 0.f) : 0.f;
        s_c2[j][co0 + 1] = ok ? fmaxf(acc[i][1], 0.f) : 0.f;
      }
    }
  }
  __syncthreads();

  // ---- stage 3: conv3  Cin=64 K=8 Cout=96, outputs j in [0,48), + relu-max epilogue
  {
    int ct = tid & 31, jg = tid >> 5;
    int co0 = ct * 3;
    float acc[6][3];
    {
      float b0 = cb3[co0], b1 = cb3[co0 + 1], b2 = cb3[co0 + 2];
#pragma unroll
      for (int i = 0; i < 6; ++i) { acc[i][0] = b0; acc[i][1] = b1; acc[i][2] = b2; }
    }
    for (int c4 = 0; c4 < 16; ++c4) {
      float a[13][4];
#pragma unroll
      for (int r = 0; r < 13; ++r) {
        float4 t4 = *(const float4*)&s_c2[jg * 6 + r][c4 * 4];
        a[r][0] = t4.x; a[r][1] = t4.y; a[r][2] = t4.z; a[r][3] = t4.w;
      }
#pragma unroll
      for (int t = 0; t < 3; ++t) {
        const float* wp = ck3 + (co0 + t) * 512 + c4 * 32;  // 32 contiguous floats
        float wf[32];
#pragma unroll
        for (int q = 0; q < 8; ++q) {
          float4 w4 = *(const float4*)(wp + q * 4);
          wf[q * 4 + 0] = w4.x; wf[q * 4 + 1] = w4.y; wf[q * 4 + 2] = w4.z; wf[q * 4 + 3] = w4.w;
        }
#pragma unroll
        for (int cc = 0; cc < 4; ++cc)
#pragma unroll
          for (int k = 0; k < 8; ++k) {
            float wv = wf[cc * 8 + k];
#pragma unroll
            for (int i = 0; i < 6; ++i) acc[i][t] += a[i + k][cc] * wv;
          }
      }
    }
    float m0 = 0.f, m1 = 0.f, m2 = 0.f;  // max(0, .) == relu folded in
#pragma unroll
    for (int i = 0; i < 6; ++i) {
      int l3 = t0 + jg * 6 + i;
      if (l3 < 997) {
        m0 = fmaxf(m0, acc[i][0]);
        m1 = fmaxf(m1, acc[i][1]);
        m2 = fmaxf(m2, acc[i][2]);
      }
    }
    atomicMax(&s_max[co0], __float_as_int(m0));
    atomicMax(&s_max[co0 + 1], __float_as_int(m1));
    atomicMax(&s_max[co0 + 2], __float_as_int(m2));
  }
  __syncthreads();
  if (tid < 96) atomicMax((int*)&outmax[b * 224 + 128 + tid], s_max[tid]);
}

// ---------------- final 256 -> 1 ----------------
__global__ void k_fc3(const float* __restrict__ in, const float* __restrict__ w,
                      const float* __restrict__ bias, float* __restrict__ out) {
  int b = blockIdx.x * 256 + threadIdx.x;
  if (b >= NB) return;
  float acc = bias[0];
#pragma unroll 4
  for (int k = 0; k < 256; ++k) acc += in[b * 256 + k] * w[k];
  out[b] = acc;
}

extern "C" void kernel_launch(void* const* d_in, const int* in_sizes, int n_in,
                              void* d_out, int out_size, void* d_ws, size_t ws_size,
                              hipStream_t stream) {
  (void)in_sizes; (void)n_in; (void)out_size; (void)ws_size;
  const float* x = (const float*)d_in[0];
  const int* ei = (const int*)d_in[1];
  const int* batch = (const int*)d_in[2];
  const int* seq = (const int*)d_in[3];
  const float* W1 = (const float*)d_in[4];
  // b1/b2/b3 (d_in[5,9,13]) dropped: constant channel bias cancels in BatchNorm
  const float* g1 = (const float*)d_in[6];
  const float* bt1 = (const float*)d_in[7];
  const float* W2 = (const float*)d_in[8];
  const float* g2 = (const float*)d_in[10];
  const float* bt2 = (const float*)d_in[11];
  const float* W3 = (const float*)d_in[12];
  const float* g3 = (const float*)d_in[14];
  const float* bt3 = (const float*)d_in[15];
  const float* emb = (const float*)d_in[16];
  const float* ck1 = (const float*)d_in[17];
  const float* cb1 = (const float*)d_in[18];
  const float* ck2 = (const float*)d_in[19];
  const float* cb2 = (const float*)d_in[20];
  const float* ck3 = (const float*)d_in[21];
  const float* cb3 = (const float*)d_in[22];
  const float* fw1 = (const float*)d_in[23];
  const float* fb1 = (const float*)d_in[24];
  const float* fw2 = (const float*)d_in[25];
  const float* fb2 = (const float*)d_in[26];
  const float* fw3 = (const float*)d_in[27];
  const float* fb3 = (const float*)d_in[28];
  const int* src = ei;
  const int* dst = ei + NE;

  float* ws = (float*)d_ws;
  float* bufA = ws;                 // 32768*128 floats (16 MB): agg / h (in-place)
  float* bufB = ws + 4194304;       // 32768*128 floats (16 MB): xw / fc scratch
  float* dis = ws + 8388608;        // 32768
  float* stats = ws + 8421376;      // 256
  float* cbuf = ws + 8421632;       // 512*224 concat features
  float* cnt2 = ws + 8536320;       // 512
  float* out = (float*)d_out;

  hipMemsetAsync(dis, 0, NN * sizeof(float), stream);
  hipMemsetAsync(cbuf, 0, NB * 224 * sizeof(float), stream);
  hipMemsetAsync(cnt2, 0, NB * sizeof(float), stream);

  k_deg<<<NE / 256, 256, 0, stream>>>(dst, dis, NE);
  k_dis<<<NN / 256, 256, 0, stream>>>(dis, NN);

  // ---- GCN layer 1 (5 -> 64)
  k_fc<64, 5, false, false><<<NN * 16 / 256, 256, 0, stream>>>(x, W1, nullptr, bufB, NN);
  k_selfscale<64><<<NN * 16 / 256, 256, 0, stream>>>(bufB, dis, bufA, NN);
  k_scatter<64><<<NE * 16 / 256, 256, 0, stream>>>(bufB, dis, src, dst, bufA, NE);
  hipMemsetAsync(stats, 0, 128 * sizeof(float), stream);
  k_bnstats<64><<<256, 256, 0, stream>>>(bufA, stats, NN);
  k_bnfinal<64><<<1, 64, 0, stream>>>(stats, g1, bt1, NN);
  k_bnrelu<64><<<NN * 16 / 256, 256, 0, stream>>>(bufA, stats, NN);

  // ---- GCN layer 2 (64 -> 128)
  k_fc<128, 64, false, false><<<NN * 32 / 256, 256, 0, stream>>>(bufA, W2, nullptr, bufB, NN);
  k_selfscale<128><<<NN * 32 / 256, 256, 0, stream>>>(bufB, dis, bufA, NN);
  k_scatter<128><<<NE * 32 / 256, 256, 0, stream>>>(bufB, dis, src, dst, bufA, NE);
  hipMemsetAsync(stats, 0, 256 * sizeof(float), stream);
  k_bnstats<128><<<256, 256, 0, stream>>>(bufA, stats, NN);
  k_bnfinal<128><<<1, 128, 0, stream>>>(stats, g2, bt2, NN);
  k_bnrelu<128><<<NN * 32 / 256, 256, 0, stream>>>(bufA, stats, NN);

  // ---- GCN layer 3 (128 -> 128)
  k_fc<128, 128, false, false><<<NN * 32 / 256, 256, 0, stream>>>(bufA, W3, nullptr, bufB, NN);
  k_selfscale<128><<<NN * 32 / 256, 256, 0, stream>>>(bufB, dis, bufA, NN);
  k_scatter<128><<<NE * 32 / 256, 256, 0, stream>>>(bufB, dis, src, dst, bufA, NE);
  hipMemsetAsync(stats, 0, 256 * sizeof(float), stream);
  k_bnstats<128><<<256, 256, 0, stream>>>(bufA, stats, NN);
  k_bnfinal<128><<<1, 128, 0, stream>>>(stats, g3, bt3, NN);
  k_bnrelu<128><<<NN * 32 / 256, 256, 0, stream>>>(bufA, stats, NN);

  // ---- graph mean pool -> cbuf[:, 0:128]
  k_pool<<<NN * 32 / 256, 256, 0, stream>>>(bufA, batch, cbuf, cnt2, NN);
  k_pooldiv<<<NB * 128 / 256, 256, 0, stream>>>(cbuf, cnt2);

  // ---- protein encoder -> cbuf[:, 128:224]
  conv_fused<<<dim3(21, NB), 256, 0, stream>>>(seq, emb, ck1, cb1, ck2, cb2, ck3, cb3, cbuf);

  // ---- regressor
  k_fc<512, 224, true, true><<<NB * 128 / 256, 256, 0, stream>>>(cbuf, fw1, fb1, bufB, NB);
  k_fc<256, 512, true, true><<<NB * 64 / 256, 256, 0, stream>>>(bufB, fw2, fb2, bufA, NB);
  k_fc3<<<2, 256, 0, stream>>>(bufA, fw3, fb3, out);
}